// Round 17
// baseline (78.105 us; speedup 1.0000x reference)
//
#include <hip/hip_runtime.h>
#include <hip/hip_bf16.h>

typedef __attribute__((ext_vector_type(8))) short short8;
typedef __attribute__((ext_vector_type(4))) float f32x4;
typedef __attribute__((ext_vector_type(16))) float f32x16;
typedef __attribute__((ext_vector_type(2))) int int2v;

#define N_TOK 8192
#define D_HALF 64
#define D_FULL 128
#define QB 128                     // q rows per block (4 sub-tiles of 32)
#define KQ 2048                    // keys per block (k-split 4)
#define CHUNK 128                  // keys staged per chunk (32KB K + 32KB V)
#define NCH (KQ / CHUNK)           // 16
#define OSTR 132
#define RSC 1.2011224087864498f    // sqrt(log2(e)): scores arrive in log2 domain
#define MFIX 94.0f                 // fixed softmax max: > 64*log2(e)=92.33 bound

// Fragment-major layouts (short8 = 16B units):
//   Kf8[(panel*16 + ks*2 + hi)*32 + li]  = K[panel*32+li][ks*16+8*hi .. +8]  (x RSC)
//   Vf8[(kc*4 + dblk)*64 + hi*32 + li]   = V^T[dblk*32+li][kc*16+8*hi .. +8] (raw)
__global__ __launch_bounds__(256) void precompute_kernel(
    const float* __restrict__ mag, const float* __restrict__ phase,
    __hip_bfloat16* __restrict__ Kf, __hip_bfloat16* __restrict__ Vf)
{
    int idx = blockIdx.x * 256 + threadIdx.x;
    if (idx >= N_TOK * D_HALF) return;
    int n = idx >> 6, d0 = idx & 63;
    float m = mag[idx], p = phase[idx];
    float s, c;
    sincosf(p, &s, &c);
    {
        float val[2] = { m * c * RSC, m * s * RSC };
        #pragma unroll
        for (int h = 0; h < 2; ++h) {
            int dc = d0 + 64 * h;
            int off = ((n >> 5) * 16 + (dc >> 4) * 2 + ((dc >> 3) & 1)) * 256
                      + (n & 31) * 8 + (dc & 7);
            Kf[off] = __float2bfloat16(val[h]);
        }
    }
    {
        float val[2] = { m, p };
        #pragma unroll
        for (int h = 0; h < 2; ++h) {
            int dv = d0 + 64 * h;
            int off = ((n >> 4) * 4 + (dv >> 5)) * 512 + ((n >> 3) & 1) * 256
                      + (dv & 31) * 8 + (n & 7);
            Vf[off] = __float2bfloat16(val[h]);
        }
    }
}

// pack two f32 into one bf16x2 word (lo=a, hi=b) -- single v_cvt_pk_bf16_f32
static __device__ __forceinline__ unsigned cvtpk(float a, float b)
{
    unsigned r;
    asm("v_cvt_pk_bf16_f32 %0, %1, %2" : "=v"(r) : "v"(a), "v"(b));
    return r;
}

// REGISTER-BLOCKED: 8 waves = (qh 0/1) x (kp 0..3); each wave owns ONE key
// panel but TWO q-subtiles (64 q rows). Each K/V fragment read from LDS
// feeds 2 MFMA (read:MFMA = 1:2) -- R11/R14/R15 all had 1:1 and all landed
// at 57-58us regardless of schedule, pinning LDS-read issue as the wall.
// Staging protocol = R14 verbatim (double-buffer, counted vmcnt(8)).
// Fixed-max softmax (bounded scores), merges = pure sums.
__global__ __launch_bounds__(512, 2) void attn_kernel(
    const short8* __restrict__ Kf8, const short8* __restrict__ Vf8,
    float* __restrict__ Opart, float* __restrict__ Sp)
{
    __shared__ __align__(16) char smem[132096];  // 2 x (K 32KB | V 32KB) + merge sums

    const int tid  = threadIdx.x;
    const int wid  = tid >> 6;     // 0..7
    const int lane = tid & 63;
    const int li   = lane & 31;
    const int hi   = lane >> 5;
    const int qh   = wid >> 2;     // q-group 0/1 (subtiles {2qh, 2qh+1})
    const int kp   = wid & 3;      // key panel 0..3 within chunk

    const int bid  = blockIdx.x;
    const int qt   = bid >> 2;     // 0..63
    const int kq   = bid & 3;      // key quarter
    const int rot  = bid & (NCH - 1);

    float (*O_lds)[32][OSTR] = (float (*)[32][OSTR])smem;   // 4 merge slots (67584B)
    float* s_base = (float*)(smem + 67584);                 // [4][32]
    auto sslot = [&](int slot) -> float* { return s_base + slot * 32; };

    auto stageKV = [&](int ck, char* lbase) {
        const char* gk = (const char*)(Kf8 + (size_t)ck * 2048);
        const char* gv = (const char*)(Vf8 + (size_t)ck * 2048);
        #pragma unroll
        for (int j = 0; j < 4; ++j)
            __builtin_amdgcn_global_load_lds(
                (const __attribute__((address_space(1))) void*)(gk + j * 8192 + tid * 16),
                (__attribute__((address_space(3))) void*)(lbase + j * 8192 + tid * 16),
                16, 0, 0);
        #pragma unroll
        for (int j = 0; j < 4; ++j)
            __builtin_amdgcn_global_load_lds(
                (const __attribute__((address_space(1))) void*)(gv + j * 8192 + tid * 16),
                (__attribute__((address_space(3))) void*)(lbase + 32768 + j * 8192 + tid * 16),
                16, 0, 0);
    };
    auto ck_of = [&](int t) { return kq * NCH + ((t + rot) & (NCH - 1)); };

    // Q fragments FIRST (oldest in vmcnt queue: 16 loads, then stages of 8)
    short8 bq[2][8];
    #pragma unroll
    for (int j = 0; j < 2; ++j) {
        const short8* qp = Kf8 + (size_t)(qt * 4 + qh * 2 + j) * 512;
        #pragma unroll
        for (int ks = 0; ks < 8; ++ks)
            bq[j][ks] = qp[(ks * 2 + hi) * 32 + li];
    }

    f32x16 acc[2][4];
    #pragma unroll
    for (int j = 0; j < 2; ++j)
        #pragma unroll
        for (int d = 0; d < 4; ++d) acc[j][d] = (f32x16)(0.0f);
    float srow[2] = { 0.0f, 0.0f };

    stageKV(ck_of(0), smem);
    stageKV(ck_of(1), smem + 65536);
    asm volatile("s_waitcnt vmcnt(8)");     // bq + S(0) retired; S(1) flying
    __builtin_amdgcn_s_barrier();

    for (int t = 0; t < NCH; ++t) {
        char* base = smem + (t & 1) * 65536;
        const short8* bK = (const short8*)base;
        const short8* bV = (const short8*)(base + 32768);

        // ---- QK^T: each K-frag read feeds BOTH q-subtiles ----
        f32x16 st0 = (f32x16)(-MFIX), st1 = (f32x16)(-MFIX);
        __builtin_amdgcn_s_setprio(1);
        #pragma unroll
        for (int ks = 0; ks < 8; ++ks) {
            short8 kf = bK[kp * 512 + (ks * 2 + hi) * 32 + li];
            st0 = __builtin_amdgcn_mfma_f32_32x32x16_bf16(kf, bq[0][ks], st0, 0, 0, 0);
            st1 = __builtin_amdgcn_mfma_f32_32x32x16_bf16(kf, bq[1][ks], st1, 0, 0, 0);
        }
        __builtin_amdgcn_s_setprio(0);

        // ---- fixed-max softmax on both subtiles; pack P (st dies) ----
        union { int w[4]; short8 v; } u0[2], u1[2];
        {
            #pragma unroll
            for (int r = 0; r < 16; ++r) st0[r] = exp2f(st0[r]);
            float sm[8];
            #pragma unroll
            for (int r = 0; r < 8; ++r) sm[r] = st0[r] + st0[r + 8];
            float ss = ((sm[0] + sm[1]) + (sm[2] + sm[3]))
                     + ((sm[4] + sm[5]) + (sm[6] + sm[7]));
            srow[0] += ss + __shfl_xor(ss, 32);
            #pragma unroll
            for (int c = 0; c < 2; ++c) {
                const int b = 8 * c;
                unsigned a0 = cvtpk(st0[b + 0], st0[b + 1]);
                unsigned a1 = cvtpk(st0[b + 2], st0[b + 3]);
                unsigned c0 = cvtpk(st0[b + 4], st0[b + 5]);
                unsigned c1 = cvtpk(st0[b + 6], st0[b + 7]);
                int2v r0 = __builtin_amdgcn_permlane32_swap((int)a0, (int)c0, false, false);
                int2v r1 = __builtin_amdgcn_permlane32_swap((int)a1, (int)c1, false, false);
                u0[c].w[0] = r0[0]; u0[c].w[1] = r1[0]; u0[c].w[2] = r0[1]; u0[c].w[3] = r1[1];
            }
        }
        {
            #pragma unroll
            for (int r = 0; r < 16; ++r) st1[r] = exp2f(st1[r]);
            float sm[8];
            #pragma unroll
            for (int r = 0; r < 8; ++r) sm[r] = st1[r] + st1[r + 8];
            float ss = ((sm[0] + sm[1]) + (sm[2] + sm[3]))
                     + ((sm[4] + sm[5]) + (sm[6] + sm[7]));
            srow[1] += ss + __shfl_xor(ss, 32);
            #pragma unroll
            for (int c = 0; c < 2; ++c) {
                const int b = 8 * c;
                unsigned a0 = cvtpk(st1[b + 0], st1[b + 1]);
                unsigned a1 = cvtpk(st1[b + 2], st1[b + 3]);
                unsigned c0 = cvtpk(st1[b + 4], st1[b + 5]);
                unsigned c1 = cvtpk(st1[b + 6], st1[b + 7]);
                int2v r0 = __builtin_amdgcn_permlane32_swap((int)a0, (int)c0, false, false);
                int2v r1 = __builtin_amdgcn_permlane32_swap((int)a1, (int)c1, false, false);
                u1[c].w[0] = r0[0]; u1[c].w[1] = r1[0]; u1[c].w[2] = r0[1]; u1[c].w[3] = r1[1];
            }
        }

        // ---- PV: each V-frag read feeds BOTH q-subtiles ----
        __builtin_amdgcn_s_setprio(1);
        #pragma unroll
        for (int c = 0; c < 2; ++c)
            #pragma unroll
            for (int d = 0; d < 4; ++d) {
                short8 vf = bV[((kp * 2 + c) * 4 + d) * 64 + hi * 32 + li];
                acc[0][d] = __builtin_amdgcn_mfma_f32_32x32x16_bf16(vf, u0[c].v, acc[0][d], 0, 0, 0);
                acc[1][d] = __builtin_amdgcn_mfma_f32_32x32x16_bf16(vf, u1[c].v, acc[1][d], 0, 0, 0);
            }
        __builtin_amdgcn_s_setprio(0);

        __builtin_amdgcn_s_barrier();            // all waves done reading buf
        if (t + 2 < NCH) {
            stageKV(ck_of(t + 2), base);         // refill this buffer
            asm volatile("s_waitcnt vmcnt(8)");  // S(t+1) landed, S(t+2) flying
        } else {
            asm volatile("s_waitcnt vmcnt(0)");  // epilogue drain
        }
        __builtin_amdgcn_s_barrier();            // next buffer ready for all
    }

    // ---- merge: two passes (j = subtile-within-group), R14 tree each ----
    __syncthreads();                         // staging dead; reuse as merge space
    #pragma unroll
    for (int j = 0; j < 2; ++j) {
        auto store_partial = [&](int slot) {
            #pragma unroll
            for (int d = 0; d < 4; ++d)
                #pragma unroll
                for (int rr = 0; rr < 4; ++rr) {
                    f32x4 v;
                    #pragma unroll
                    for (int jj = 0; jj < 4; ++jj) v[jj] = acc[j][d][4 * rr + jj];
                    *reinterpret_cast<f32x4*>(&O_lds[slot][li][d * 32 + 8 * rr + 4 * hi]) = v;
                }
            if (hi == 0) sslot(slot)[li] = srow[j];
        };
        auto merge_partial = [&](int slot) {
            srow[j] += sslot(slot)[li];
            #pragma unroll
            for (int d = 0; d < 4; ++d)
                #pragma unroll
                for (int rr = 0; rr < 4; ++rr) {
                    f32x4 v = *reinterpret_cast<const f32x4*>(&O_lds[slot][li][d * 32 + 8 * rr + 4 * hi]);
                    #pragma unroll
                    for (int jj = 0; jj < 4; ++jj)
                        acc[j][d][4 * rr + jj] += v[jj];
                }
        };

        if (kp >= 2) store_partial(qh * 2 + (kp - 2));   // 4 waves -> slots 0..3
        __syncthreads();
        if (kp < 2) merge_partial(qh * 2 + kp);
        __syncthreads();
        if (kp == 1) store_partial(qh);                  // 2 waves -> slots 0,1
        __syncthreads();
        if (kp == 0) merge_partial(qh);
        __syncthreads();
        if (kp == 0) store_partial(qh);                  // totals -> slots 0,1
        __syncthreads();

        // write this pass's 64 q rows (subtiles 2*grp + j), unnormalized + S
        #pragma unroll
        for (int u0i = 0; u0i < 2; ++u0i) {
            int u  = tid + u0i * 512;          // 0..1023
            int q64 = u >> 4;                  // 0..63
            int dg  = (u & 15) * 8;            // 0..120
            int grp = q64 >> 5, qq = q64 & 31;
            int qglob = (grp * 2 + j) * 32 + qq;
            f32x4 o0 = *reinterpret_cast<const f32x4*>(&O_lds[grp][qq][dg]);
            f32x4 o1 = *reinterpret_cast<const f32x4*>(&O_lds[grp][qq][dg + 4]);
            size_t pidx = (size_t)bid * QB + qglob;
            *reinterpret_cast<f32x4*>(&Opart[pidx * D_FULL + dg])     = o0;
            *reinterpret_cast<f32x4*>(&Opart[pidx * D_FULL + dg + 4]) = o1;
            if (dg == 0) Sp[pidx] = sslot(grp)[qq];
        }
        __syncthreads();                       // readers done before next pass
    }
}

// combine the four k-quarter partials per q-row (pure sums) and normalize
__global__ __launch_bounds__(256) void merge4_kernel(
    const float* __restrict__ Opart, const float* __restrict__ Sp,
    float* __restrict__ out)
{
    int i   = blockIdx.x * 256 + threadIdx.x;   // 262144 total, 4 floats each
    int row = i >> 5;                           // 0..8191
    int dg  = (i & 31) * 4;                     // 0..124
    int qt  = row >> 7, qq = row & 127;
    size_t pidx[4];
    float S = 0.0f;
    #pragma unroll
    for (int k = 0; k < 4; ++k) {
        pidx[k] = (size_t)(qt * 4 + k) * QB + qq;
        S += Sp[pidx[k]];
    }
    float inv = 1.0f / S;
    f32x4 o = (f32x4)(0.0f);
    #pragma unroll
    for (int k = 0; k < 4; ++k) {
        f32x4 a = *reinterpret_cast<const f32x4*>(&Opart[pidx[k] * D_FULL + dg]);
        #pragma unroll
        for (int jj = 0; jj < 4; ++jj) o[jj] += a[jj];
    }
    #pragma unroll
    for (int jj = 0; jj < 4; ++jj) o[jj] *= inv;
    float* dst = (dg < D_HALF)
        ? out + (size_t)row * D_HALF + dg
        : out + (size_t)N_TOK * D_HALF + (size_t)row * D_HALF + (dg - D_HALF);
    *reinterpret_cast<f32x4*>(dst) = o;
}

extern "C" void kernel_launch(void* const* d_in, const int* in_sizes, int n_in,
                              void* d_out, int out_size, void* d_ws, size_t ws_size,
                              hipStream_t stream)
{
    const float* mag   = (const float*)d_in[0];
    const float* phase = (const float*)d_in[1];
    float* out = (float*)d_out;

    char* ws = (char*)d_ws;
    __hip_bfloat16* Kf = (__hip_bfloat16*)ws;                    // 2 MB
    __hip_bfloat16* Vf = Kf + (size_t)N_TOK * D_FULL;            // 2 MB
    float* Opart = (float*)(ws + 4u * 1024 * 1024);              // 16 MB
    float* Sp    = (float*)(ws + 20u * 1024 * 1024);             // 128 KB

    precompute_kernel<<<(N_TOK * D_HALF + 255) / 256, 256, 0, stream>>>(mag, phase, Kf, Vf);
    attn_kernel<<<256, 512, 0, stream>>>((const short8*)Kf, (const short8*)Vf, Opart, Sp);
    merge4_kernel<<<1024, 256, 0, stream>>>(Opart, Sp, out);
}

// Round 18
// 63.224 us; speedup vs baseline: 1.2354x; 1.2354x over previous
//
#include <hip/hip_runtime.h>
#include <hip/hip_bf16.h>

typedef __attribute__((ext_vector_type(8))) short short8;
typedef __attribute__((ext_vector_type(4))) float f32x4;
typedef __attribute__((ext_vector_type(16))) float f32x16;
typedef __attribute__((ext_vector_type(2))) int int2v;

#define N_TOK 8192
#define D_HALF 64
#define D_FULL 128
#define QB 128                     // q rows per block (4 sub-tiles of 32)
#define KQ 2048                    // keys per block (k-split 4)
#define CHUNK 128                  // keys staged per chunk (32KB K + 32KB V)
#define NCH (KQ / CHUNK)           // 16
#define OSTR 132
#define RSC 1.2011224087864498f    // sqrt(log2(e)): scores arrive in log2 domain
#define MFIX 94.0f                 // fixed softmax max: > 64*log2(e)=92.33 bound

// Fragment-major layouts (short8 = 16B units):
//   Kf8[(panel*16 + ks*2 + hi)*32 + li]  = K[panel*32+li][ks*16+8*hi .. +8]  (x RSC)
//   Vf8[(kc*4 + dblk)*64 + hi*32 + li]   = V^T[dblk*32+li][kc*16+8*hi .. +8] (raw)
__global__ __launch_bounds__(256) void precompute_kernel(
    const float* __restrict__ mag, const float* __restrict__ phase,
    __hip_bfloat16* __restrict__ Kf, __hip_bfloat16* __restrict__ Vf)
{
    int idx = blockIdx.x * 256 + threadIdx.x;
    if (idx >= N_TOK * D_HALF) return;
    int n = idx >> 6, d0 = idx & 63;
    float m = mag[idx], p = phase[idx];
    float s, c;
    sincosf(p, &s, &c);
    {
        float val[2] = { m * c * RSC, m * s * RSC };
        #pragma unroll
        for (int h = 0; h < 2; ++h) {
            int dc = d0 + 64 * h;
            int off = ((n >> 5) * 16 + (dc >> 4) * 2 + ((dc >> 3) & 1)) * 256
                      + (n & 31) * 8 + (dc & 7);
            Kf[off] = __float2bfloat16(val[h]);
        }
    }
    {
        float val[2] = { m, p };
        #pragma unroll
        for (int h = 0; h < 2; ++h) {
            int dv = d0 + 64 * h;
            int off = ((n >> 4) * 4 + (dv >> 5)) * 512 + ((n >> 3) & 1) * 256
                      + (dv & 31) * 8 + (n & 7);
            Vf[off] = __float2bfloat16(val[h]);
        }
    }
}

// pack two f32 into one bf16x2 word (lo=a, hi=b) -- single v_cvt_pk_bf16_f32
static __device__ __forceinline__ unsigned cvtpk(float a, float b)
{
    unsigned r;
    asm("v_cvt_pk_bf16_f32 %0, %1, %2" : "=v"(r) : "v"(a), "v"(b));
    return r;
}

// R14 verbatim main loop (best verified: 57.6us): counted-vmcnt double-buffer
// DMA pipeline, fixed-max softmax (scores bounded by 64*log2e<94 in log2
// domain -> no running max / rescale; subtract folded into MFMA C-init),
// merges = pure sums. R17's register-blocking spilled (VGPR 128 cap + 27MB
// scratch WRITE) -> reverted. This round: Opart stored bf16 (same exponent
// range as f32; partials ~2^-80 stay normal) to halve merge4 traffic.
__global__ __launch_bounds__(512, 2) void attn_kernel(
    const short8* __restrict__ Kf8, const short8* __restrict__ Vf8,
    __hip_bfloat16* __restrict__ Opart, float* __restrict__ Sp)
{
    __shared__ __align__(16) char smem[132096];  // 2 x (K 32KB | V 32KB) + merge sums

    const int tid  = threadIdx.x;
    const int wid  = tid >> 6;     // 0..7
    const int lane = tid & 63;
    const int li   = lane & 31;
    const int hi   = lane >> 5;
    const int qh   = wid >> 1;     // q sub-tile 0..3
    const int kp   = wid & 1;      // key panel group

    const int bid  = blockIdx.x;
    const int qt   = bid >> 2;     // 0..63
    const int kq   = bid & 3;      // key quarter
    const int rot  = bid & (NCH - 1);

    float (*O_lds)[32][OSTR] = (float (*)[32][OSTR])smem;   // merge reuse
    float* s_base = (float*)(smem + 67584);                 // [4][32]
    auto sslot = [&](int slot) -> float* { return s_base + slot * 32; };

    auto stageKV = [&](int ck, char* lbase) {
        const char* gk = (const char*)(Kf8 + (size_t)ck * 2048);
        const char* gv = (const char*)(Vf8 + (size_t)ck * 2048);
        #pragma unroll
        for (int j = 0; j < 4; ++j)
            __builtin_amdgcn_global_load_lds(
                (const __attribute__((address_space(1))) void*)(gk + j * 8192 + tid * 16),
                (__attribute__((address_space(3))) void*)(lbase + j * 8192 + tid * 16),
                16, 0, 0);
        #pragma unroll
        for (int j = 0; j < 4; ++j)
            __builtin_amdgcn_global_load_lds(
                (const __attribute__((address_space(1))) void*)(gv + j * 8192 + tid * 16),
                (__attribute__((address_space(3))) void*)(lbase + 32768 + j * 8192 + tid * 16),
                16, 0, 0);
    };
    auto ck_of = [&](int t) { return kq * NCH + ((t + rot) & (NCH - 1)); };

    // Q fragments FIRST (oldest in vmcnt queue, so counted waits stay exact)
    short8 bq[8];
    {
        const short8* qp = Kf8 + (size_t)(qt * 4 + qh) * 512;
        #pragma unroll
        for (int ks = 0; ks < 8; ++ks)
            bq[ks] = qp[(ks * 2 + hi) * 32 + li];
    }

    f32x16 acc[4];
    #pragma unroll
    for (int d = 0; d < 4; ++d) acc[d] = (f32x16)(0.0f);
    float srow = 0.0f;

    stageKV(ck_of(0), smem);
    stageKV(ck_of(1), smem + 65536);
    asm volatile("s_waitcnt vmcnt(8)");     // bq + S(0) retired; S(1) flying
    __builtin_amdgcn_s_barrier();

    for (int t = 0; t < NCH; ++t) {
        char* base = smem + (t & 1) * 65536;
        const short8* ldsK = (const short8*)base;
        const short8* ldsV = (const short8*)(base + 32768);

        #pragma unroll
        for (int pp = 0; pp < 2; ++pp) {
            const int panel = kp + 2 * pp;

            // ---- S^T = K.Q, C-init = -MFIX folds the softmax subtract ----
            f32x16 st = (f32x16)(-MFIX);
            __builtin_amdgcn_s_setprio(1);
            #pragma unroll
            for (int ks = 0; ks < 8; ++ks) {
                short8 kf = ldsK[panel * 512 + (ks * 2 + hi) * 32 + li];
                st = __builtin_amdgcn_mfma_f32_32x32x16_bf16(kf, bq[ks], st, 0, 0, 0);
            }
            __builtin_amdgcn_s_setprio(0);

            // ---- P = exp2(st); row-sum only (no max machinery) ----
            #pragma unroll
            for (int r = 0; r < 16; ++r) st[r] = exp2f(st[r]);
            float sm[8];
            #pragma unroll
            for (int r = 0; r < 8; ++r) sm[r] = st[r] + st[r + 8];
            float ss = ((sm[0] + sm[1]) + (sm[2] + sm[3]))
                     + ((sm[4] + sm[5]) + (sm[6] + sm[7]));
            srow += ss + __shfl_xor(ss, 32);

            // ---- PV: pack P (cvt_pk) -> permlane repack -> 8 MFMA ----
            #pragma unroll
            for (int c = 0; c < 2; ++c) {
                const int b = 8 * c;
                unsigned a0 = cvtpk(st[b + 0], st[b + 1]);
                unsigned a1 = cvtpk(st[b + 2], st[b + 3]);
                unsigned b0 = cvtpk(st[b + 4], st[b + 5]);
                unsigned b1 = cvtpk(st[b + 6], st[b + 7]);
                int2v r0 = __builtin_amdgcn_permlane32_swap((int)a0, (int)b0, false, false);
                int2v r1 = __builtin_amdgcn_permlane32_swap((int)a1, (int)b1, false, false);
                union { int w[4]; short8 v; } u;
                u.w[0] = r0[0]; u.w[1] = r1[0]; u.w[2] = r0[1]; u.w[3] = r1[1];

                const short8* vp = ldsV + (panel * 2 + c) * 256 + hi * 32 + li;
                __builtin_amdgcn_s_setprio(1);
                #pragma unroll
                for (int d = 0; d < 4; ++d) {
                    short8 vf = vp[d * 64];
                    acc[d] = __builtin_amdgcn_mfma_f32_32x32x16_bf16(vf, u.v, acc[d], 0, 0, 0);
                }
                __builtin_amdgcn_s_setprio(0);
            }
        }

        __builtin_amdgcn_s_barrier();            // all waves done reading buf
        if (t + 2 < NCH) {
            stageKV(ck_of(t + 2), base);         // refill this buffer
            asm volatile("s_waitcnt vmcnt(8)");  // S(t+1) landed, S(t+2) flying
        } else {
            asm volatile("s_waitcnt vmcnt(0)");  // epilogue drain
        }
        __builtin_amdgcn_s_barrier();            // next buffer ready for all
    }

    // ---- in-block merge over kp (pure sums; fixed max everywhere) ----
    auto store_partial = [&](int slot) {
        #pragma unroll
        for (int d = 0; d < 4; ++d)
            #pragma unroll
            for (int rr = 0; rr < 4; ++rr) {
                f32x4 v;
                #pragma unroll
                for (int j = 0; j < 4; ++j) v[j] = acc[d][4 * rr + j];
                *reinterpret_cast<f32x4*>(&O_lds[slot][li][d * 32 + 8 * rr + 4 * hi]) = v;
            }
        if (hi == 0) sslot(slot)[li] = srow;
    };
    auto merge_partial = [&](int slot) {
        srow += sslot(slot)[li];
        #pragma unroll
        for (int d = 0; d < 4; ++d)
            #pragma unroll
            for (int rr = 0; rr < 4; ++rr) {
                f32x4 v = *reinterpret_cast<const f32x4*>(&O_lds[slot][li][d * 32 + 8 * rr + 4 * hi]);
                #pragma unroll
                for (int j = 0; j < 4; ++j)
                    acc[d][4 * rr + j] += v[j];
            }
    };

    __syncthreads();                         // staging dead; reuse as merge space
    if (kp == 1) store_partial(qh);
    __syncthreads();
    if (kp == 0) merge_partial(qh);
    __syncthreads();
    if (kp == 0) store_partial(qh);
    __syncthreads();

    // ---- write UNNORMALIZED per-block partial as bf16 (halves traffic) ----
    #pragma unroll
    for (int u0 = 0; u0 < 4; ++u0) {
        int u  = tid + u0 * 512;           // 0..2047
        int q  = u >> 4;                   // 0..127
        int dg = (u & 15) * 8;             // 0..120
        int grp = q >> 5, qq = q & 31;
        f32x4 o0 = *reinterpret_cast<const f32x4*>(&O_lds[grp][qq][dg]);
        f32x4 o1 = *reinterpret_cast<const f32x4*>(&O_lds[grp][qq][dg + 4]);
        union { unsigned w[4]; short8 v; } pk;
        pk.w[0] = cvtpk(o0[0], o0[1]);
        pk.w[1] = cvtpk(o0[2], o0[3]);
        pk.w[2] = cvtpk(o1[0], o1[1]);
        pk.w[3] = cvtpk(o1[2], o1[3]);
        size_t pidx = (size_t)bid * QB + q;
        *reinterpret_cast<short8*>(&Opart[pidx * D_FULL + dg]) = pk.v;
        if (dg == 0) Sp[pidx] = sslot(grp)[qq];   // merged sum from LDS (f32)
    }
}

// combine the four k-quarter bf16 partials per q-row (pure sums), normalize
__global__ __launch_bounds__(256) void merge4_kernel(
    const __hip_bfloat16* __restrict__ Opart, const float* __restrict__ Sp,
    float* __restrict__ out)
{
    int i   = blockIdx.x * 256 + threadIdx.x;   // 131072 total, 8 floats each
    int row = i >> 4;                           // 0..8191
    int dg  = (i & 15) * 8;                     // 0..120
    int qt  = row >> 7, qq = row & 127;
    float S = 0.0f;
    f32x4 o0 = (f32x4)(0.0f), o1 = (f32x4)(0.0f);
    #pragma unroll
    for (int k = 0; k < 4; ++k) {
        size_t pidx = (size_t)(qt * 4 + k) * QB + qq;
        S += Sp[pidx];
        short8 v = *reinterpret_cast<const short8*>(&Opart[pidx * D_FULL + dg]);
        #pragma unroll
        for (int j = 0; j < 8; ++j) {
            unsigned short us = (unsigned short)v[j];
            unsigned wu = ((unsigned)us) << 16;
            float f = *reinterpret_cast<float*>(&wu);
            if (j < 4) o0[j] += f; else o1[j - 4] += f;
        }
    }
    float inv = 1.0f / S;
    #pragma unroll
    for (int j = 0; j < 4; ++j) { o0[j] *= inv; o1[j] *= inv; }
    float* dst = (dg < D_HALF)
        ? out + (size_t)row * D_HALF + dg
        : out + (size_t)N_TOK * D_HALF + (size_t)row * D_HALF + (dg - D_HALF);
    *reinterpret_cast<f32x4*>(dst)     = o0;
    *reinterpret_cast<f32x4*>(dst + 4) = o1;
}

extern "C" void kernel_launch(void* const* d_in, const int* in_sizes, int n_in,
                              void* d_out, int out_size, void* d_ws, size_t ws_size,
                              hipStream_t stream)
{
    const float* mag   = (const float*)d_in[0];
    const float* phase = (const float*)d_in[1];
    float* out = (float*)d_out;

    char* ws = (char*)d_ws;
    __hip_bfloat16* Kf = (__hip_bfloat16*)ws;                    // 2 MB
    __hip_bfloat16* Vf = Kf + (size_t)N_TOK * D_FULL;            // 2 MB
    __hip_bfloat16* Opart = (__hip_bfloat16*)(ws + 4u * 1024 * 1024);  // 8 MB
    float* Sp = (float*)(ws + 13u * 1024 * 1024);                // 128 KB

    precompute_kernel<<<(N_TOK * D_HALF + 255) / 256, 256, 0, stream>>>(mag, phase, Kf, Vf);
    attn_kernel<<<256, 512, 0, stream>>>((const short8*)Kf, (const short8*)Vf, Opart, Sp);
    merge4_kernel<<<512, 256, 0, stream>>>(Opart, Sp, out);
}

// Round 19
// 61.491 us; speedup vs baseline: 1.2702x; 1.0282x over previous
//
#include <hip/hip_runtime.h>
#include <hip/hip_bf16.h>

typedef __attribute__((ext_vector_type(8))) short short8;
typedef __attribute__((ext_vector_type(4))) float f32x4;
typedef __attribute__((ext_vector_type(16))) float f32x16;
typedef __attribute__((ext_vector_type(2))) int int2v;

#define N_TOK 8192
#define D_HALF 64
#define D_FULL 128
#define QB 128                     // q rows per block (4 sub-tiles of 32)
#define KQ 2048                    // keys per block (k-split 4)
#define CHUNK 128                  // keys staged per chunk (32KB K + 32KB V)
#define NCH (KQ / CHUNK)           // 16
#define OSTR 132
#define RSC 1.2011224087864498f    // sqrt(log2(e)): scores arrive in log2 domain
#define MFIX 94.0f                 // fixed softmax max: > 64*log2(e)=92.33 bound

// pack two f32 into one bf16x2 word (lo=a, hi=b) -- single v_cvt_pk_bf16_f32
static __device__ __forceinline__ unsigned cvtpk(float a, float b)
{
    unsigned r;
    asm("v_cvt_pk_bf16_f32 %0, %1, %2" : "=v"(r) : "v"(a), "v"(b));
    return r;
}

// Fused precompute, vectorized 16B stores (G13):
//  blocks 0..255   : K-pack. thread=(n, db): 8 sincos, two short8 stores.
//     Kf elem off for (n, dc=db*8+j, half h) = ((n>>5)*16 + db + 8h)*256
//                                              + (n&31)*8 + j   (verified)
//  blocks 256..767 : V-pack via LDS transpose. tile=(32 n x 64 d) of one
//     input; thread=(dv, nb): one short8 store at
//     off8 = ((n0>>4)*4 + (dv_eff>>5))*64 + ((n0>>3)&1)*32 + (dv_eff&31).
__global__ __launch_bounds__(256) void precompute_kernel(
    const float* __restrict__ mag, const float* __restrict__ phase,
    __hip_bfloat16* __restrict__ Kf, __hip_bfloat16* __restrict__ Vf)
{
    const int bid = blockIdx.x;
    const int tid = threadIdx.x;

    if (bid < 256) {
        // ---- K-pack ----
        int g  = bid * 256 + tid;        // 65536 threads
        int n  = g >> 3;
        int db = g & 7;
        const f32x4* mp = reinterpret_cast<const f32x4*>(mag + (size_t)n * 64 + db * 8);
        const f32x4* pp = reinterpret_cast<const f32x4*>(phase + (size_t)n * 64 + db * 8);
        f32x4 m0 = mp[0], m1 = mp[1];
        f32x4 p0 = pp[0], p1 = pp[1];
        float kc[8], ks_[8];
        #pragma unroll
        for (int j = 0; j < 4; ++j) {
            float s, c;
            sincosf(p0[j], &s, &c);
            kc[j]  = m0[j] * c * RSC;
            ks_[j] = m0[j] * s * RSC;
        }
        #pragma unroll
        for (int j = 0; j < 4; ++j) {
            float s, c;
            sincosf(p1[j], &s, &c);
            kc[4 + j]  = m1[j] * c * RSC;
            ks_[4 + j] = m1[j] * s * RSC;
        }
        union { unsigned w[4]; short8 v; } vc, vs;
        #pragma unroll
        for (int j = 0; j < 4; ++j) {
            vc.w[j] = cvtpk(kc[2 * j], kc[2 * j + 1]);
            vs.w[j] = cvtpk(ks_[2 * j], ks_[2 * j + 1]);
        }
        short8* K8 = reinterpret_cast<short8*>(Kf);
        int offc = ((n >> 5) * 16 + db) * 32 + (n & 31);       // short8 units
        int offs = ((n >> 5) * 16 + 8 + db) * 32 + (n & 31);
        K8[offc] = vc.v;
        K8[offs] = vs.v;
    } else {
        // ---- V-pack (LDS transpose; no trig) ----
        __shared__ float T[32][65];
        int vb   = bid - 256;            // 0..511
        int tile = vb >> 1;              // 0..255 (32-row tiles)
        int h    = vb & 1;               // 0 = mag, 1 = phase
        const float* src = h ? phase : mag;

        // load 32x64 f32 tile, coalesced (lane j covers 32B of row r)
        {
            int r = tid >> 3, cp = (tid & 7) * 8;
            const f32x4* sp = reinterpret_cast<const f32x4*>(src + ((size_t)tile * 32 + r) * 64 + cp);
            f32x4 a = sp[0], b = sp[1];
            #pragma unroll
            for (int j = 0; j < 4; ++j) { T[r][cp + j] = a[j]; T[r][cp + 4 + j] = b[j]; }
        }
        __syncthreads();

        int dv = tid & 63;               // local d
        int nb = tid >> 6;               // 0..3 (8-row blocks)
        int n0 = tile * 32 + nb * 8;
        int dv_eff = dv + 64 * h;
        union { unsigned w[4]; short8 v; } pk;
        #pragma unroll
        for (int j = 0; j < 4; ++j)
            pk.w[j] = cvtpk(T[nb * 8 + 2 * j][dv], T[nb * 8 + 2 * j + 1][dv]);
        short8* V8 = reinterpret_cast<short8*>(Vf);
        int off8 = ((n0 >> 4) * 4 + (dv_eff >> 5)) * 64 + ((n0 >> 3) & 1) * 32 + (dv_eff & 31);
        V8[off8] = pk.v;
    }
}

// R14/R18 main loop (best verified: 56.2us attn): counted-vmcnt double-buffer
// DMA pipeline, fixed-max softmax (scores bounded by 64*log2e<94 in log2
// domain -> no running max / rescale; subtract folded into MFMA C-init),
// merges = pure sums, bf16 partials. Structural floor audited R19: five
// variants pinned at 56-58us = m233's measured 2-phase template ceiling;
// 4 waves/SIMD blocked by 152-reg wave state, CHUNK>128 by LDS capacity.
__global__ __launch_bounds__(512, 2) void attn_kernel(
    const short8* __restrict__ Kf8, const short8* __restrict__ Vf8,
    __hip_bfloat16* __restrict__ Opart, float* __restrict__ Sp)
{
    __shared__ __align__(16) char smem[132096];  // 2 x (K 32KB | V 32KB) + merge sums

    const int tid  = threadIdx.x;
    const int wid  = tid >> 6;     // 0..7
    const int lane = tid & 63;
    const int li   = lane & 31;
    const int hi   = lane >> 5;
    const int qh   = wid >> 1;     // q sub-tile 0..3
    const int kp   = wid & 1;      // key panel group

    const int bid  = blockIdx.x;
    const int qt   = bid >> 2;     // 0..63
    const int kq   = bid & 3;      // key quarter
    const int rot  = bid & (NCH - 1);

    float (*O_lds)[32][OSTR] = (float (*)[32][OSTR])smem;   // merge reuse
    float* s_base = (float*)(smem + 67584);                 // [4][32]
    auto sslot = [&](int slot) -> float* { return s_base + slot * 32; };

    auto stageKV = [&](int ck, char* lbase) {
        const char* gk = (const char*)(Kf8 + (size_t)ck * 2048);
        const char* gv = (const char*)(Vf8 + (size_t)ck * 2048);
        #pragma unroll
        for (int j = 0; j < 4; ++j)
            __builtin_amdgcn_global_load_lds(
                (const __attribute__((address_space(1))) void*)(gk + j * 8192 + tid * 16),
                (__attribute__((address_space(3))) void*)(lbase + j * 8192 + tid * 16),
                16, 0, 0);
        #pragma unroll
        for (int j = 0; j < 4; ++j)
            __builtin_amdgcn_global_load_lds(
                (const __attribute__((address_space(1))) void*)(gv + j * 8192 + tid * 16),
                (__attribute__((address_space(3))) void*)(lbase + 32768 + j * 8192 + tid * 16),
                16, 0, 0);
    };
    auto ck_of = [&](int t) { return kq * NCH + ((t + rot) & (NCH - 1)); };

    // Q fragments FIRST (oldest in vmcnt queue, so counted waits stay exact)
    short8 bq[8];
    {
        const short8* qp = Kf8 + (size_t)(qt * 4 + qh) * 512;
        #pragma unroll
        for (int ks = 0; ks < 8; ++ks)
            bq[ks] = qp[(ks * 2 + hi) * 32 + li];
    }

    f32x16 acc[4];
    #pragma unroll
    for (int d = 0; d < 4; ++d) acc[d] = (f32x16)(0.0f);
    float srow = 0.0f;

    stageKV(ck_of(0), smem);
    stageKV(ck_of(1), smem + 65536);
    asm volatile("s_waitcnt vmcnt(8)");     // bq + S(0) retired; S(1) flying
    __builtin_amdgcn_s_barrier();

    for (int t = 0; t < NCH; ++t) {
        char* base = smem + (t & 1) * 65536;
        const short8* ldsK = (const short8*)base;
        const short8* ldsV = (const short8*)(base + 32768);

        #pragma unroll
        for (int pp = 0; pp < 2; ++pp) {
            const int panel = kp + 2 * pp;

            // ---- S^T = K.Q, C-init = -MFIX folds the softmax subtract ----
            f32x16 st = (f32x16)(-MFIX);
            __builtin_amdgcn_s_setprio(1);
            #pragma unroll
            for (int ks = 0; ks < 8; ++ks) {
                short8 kf = ldsK[panel * 512 + (ks * 2 + hi) * 32 + li];
                st = __builtin_amdgcn_mfma_f32_32x32x16_bf16(kf, bq[ks], st, 0, 0, 0);
            }
            __builtin_amdgcn_s_setprio(0);

            // ---- P = exp2(st); row-sum only (no max machinery) ----
            #pragma unroll
            for (int r = 0; r < 16; ++r) st[r] = exp2f(st[r]);
            float sm[8];
            #pragma unroll
            for (int r = 0; r < 8; ++r) sm[r] = st[r] + st[r + 8];
            float ss = ((sm[0] + sm[1]) + (sm[2] + sm[3]))
                     + ((sm[4] + sm[5]) + (sm[6] + sm[7]));
            srow += ss + __shfl_xor(ss, 32);

            // ---- PV: pack P (cvt_pk) -> permlane repack -> 8 MFMA ----
            #pragma unroll
            for (int c = 0; c < 2; ++c) {
                const int b = 8 * c;
                unsigned a0 = cvtpk(st[b + 0], st[b + 1]);
                unsigned a1 = cvtpk(st[b + 2], st[b + 3]);
                unsigned b0 = cvtpk(st[b + 4], st[b + 5]);
                unsigned b1 = cvtpk(st[b + 6], st[b + 7]);
                int2v r0 = __builtin_amdgcn_permlane32_swap((int)a0, (int)b0, false, false);
                int2v r1 = __builtin_amdgcn_permlane32_swap((int)a1, (int)b1, false, false);
                union { int w[4]; short8 v; } u;
                u.w[0] = r0[0]; u.w[1] = r1[0]; u.w[2] = r0[1]; u.w[3] = r1[1];

                const short8* vp = ldsV + (panel * 2 + c) * 256 + hi * 32 + li;
                __builtin_amdgcn_s_setprio(1);
                #pragma unroll
                for (int d = 0; d < 4; ++d) {
                    short8 vf = vp[d * 64];
                    acc[d] = __builtin_amdgcn_mfma_f32_32x32x16_bf16(vf, u.v, acc[d], 0, 0, 0);
                }
                __builtin_amdgcn_s_setprio(0);
            }
        }

        __builtin_amdgcn_s_barrier();            // all waves done reading buf
        if (t + 2 < NCH) {
            stageKV(ck_of(t + 2), base);         // refill this buffer
            asm volatile("s_waitcnt vmcnt(8)");  // S(t+1) landed, S(t+2) flying
        } else {
            asm volatile("s_waitcnt vmcnt(0)");  // epilogue drain
        }
        __builtin_amdgcn_s_barrier();            // next buffer ready for all
    }

    // ---- in-block merge over kp (pure sums; fixed max everywhere) ----
    auto store_partial = [&](int slot) {
        #pragma unroll
        for (int d = 0; d < 4; ++d)
            #pragma unroll
            for (int rr = 0; rr < 4; ++rr) {
                f32x4 v;
                #pragma unroll
                for (int j = 0; j < 4; ++j) v[j] = acc[d][4 * rr + j];
                *reinterpret_cast<f32x4*>(&O_lds[slot][li][d * 32 + 8 * rr + 4 * hi]) = v;
            }
        if (hi == 0) sslot(slot)[li] = srow;
    };
    auto merge_partial = [&](int slot) {
        srow += sslot(slot)[li];
        #pragma unroll
        for (int d = 0; d < 4; ++d)
            #pragma unroll
            for (int rr = 0; rr < 4; ++rr) {
                f32x4 v = *reinterpret_cast<const f32x4*>(&O_lds[slot][li][d * 32 + 8 * rr + 4 * hi]);
                #pragma unroll
                for (int j = 0; j < 4; ++j)
                    acc[d][4 * rr + j] += v[j];
            }
    };

    __syncthreads();                         // staging dead; reuse as merge space
    if (kp == 1) store_partial(qh);
    __syncthreads();
    if (kp == 0) merge_partial(qh);
    __syncthreads();
    if (kp == 0) store_partial(qh);
    __syncthreads();

    // ---- write UNNORMALIZED per-block partial as bf16 (halves traffic) ----
    #pragma unroll
    for (int u0 = 0; u0 < 4; ++u0) {
        int u  = tid + u0 * 512;           // 0..2047
        int q  = u >> 4;                   // 0..127
        int dg = (u & 15) * 8;             // 0..120
        int grp = q >> 5, qq = q & 31;
        f32x4 o0 = *reinterpret_cast<const f32x4*>(&O_lds[grp][qq][dg]);
        f32x4 o1 = *reinterpret_cast<const f32x4*>(&O_lds[grp][qq][dg + 4]);
        union { unsigned w[4]; short8 v; } pk;
        pk.w[0] = cvtpk(o0[0], o0[1]);
        pk.w[1] = cvtpk(o0[2], o0[3]);
        pk.w[2] = cvtpk(o1[0], o1[1]);
        pk.w[3] = cvtpk(o1[2], o1[3]);
        size_t pidx = (size_t)bid * QB + q;
        *reinterpret_cast<short8*>(&Opart[pidx * D_FULL + dg]) = pk.v;
        if (dg == 0) Sp[pidx] = sslot(grp)[qq];   // merged sum from LDS (f32)
    }
}

// combine the four k-quarter bf16 partials per q-row (pure sums), normalize
__global__ __launch_bounds__(256) void merge4_kernel(
    const __hip_bfloat16* __restrict__ Opart, const float* __restrict__ Sp,
    float* __restrict__ out)
{
    int i   = blockIdx.x * 256 + threadIdx.x;   // 131072 total, 8 floats each
    int row = i >> 4;                           // 0..8191
    int dg  = (i & 15) * 8;                     // 0..120
    int qt  = row >> 7, qq = row & 127;
    float S = 0.0f;
    f32x4 o0 = (f32x4)(0.0f), o1 = (f32x4)(0.0f);
    #pragma unroll
    for (int k = 0; k < 4; ++k) {
        size_t pidx = (size_t)(qt * 4 + k) * QB + qq;
        S += Sp[pidx];
        short8 v = *reinterpret_cast<const short8*>(&Opart[pidx * D_FULL + dg]);
        #pragma unroll
        for (int j = 0; j < 8; ++j) {
            unsigned short us = (unsigned short)v[j];
            unsigned wu = ((unsigned)us) << 16;
            float f = *reinterpret_cast<float*>(&wu);
            if (j < 4) o0[j] += f; else o1[j - 4] += f;
        }
    }
    float inv = 1.0f / S;
    #pragma unroll
    for (int j = 0; j < 4; ++j) { o0[j] *= inv; o1[j] *= inv; }
    float* dst = (dg < D_HALF)
        ? out + (size_t)row * D_HALF + dg
        : out + (size_t)N_TOK * D_HALF + (size_t)row * D_HALF + (dg - D_HALF);
    *reinterpret_cast<f32x4*>(dst)     = o0;
    *reinterpret_cast<f32x4*>(dst + 4) = o1;
}

extern "C" void kernel_launch(void* const* d_in, const int* in_sizes, int n_in,
                              void* d_out, int out_size, void* d_ws, size_t ws_size,
                              hipStream_t stream)
{
    const float* mag   = (const float*)d_in[0];
    const float* phase = (const float*)d_in[1];
    float* out = (float*)d_out;

    char* ws = (char*)d_ws;
    __hip_bfloat16* Kf = (__hip_bfloat16*)ws;                    // 2 MB
    __hip_bfloat16* Vf = Kf + (size_t)N_TOK * D_FULL;            // 2 MB
    __hip_bfloat16* Opart = (__hip_bfloat16*)(ws + 4u * 1024 * 1024);  // 8 MB
    float* Sp = (float*)(ws + 13u * 1024 * 1024);                // 128 KB

    precompute_kernel<<<768, 256, 0, stream>>>(mag, phase, Kf, Vf);
    attn_kernel<<<256, 512, 0, stream>>>((const short8*)Kf, (const short8*)Vf, Opart, Sp);
    merge4_kernel<<<512, 256, 0, stream>>>(Opart, Sp, out);
}

// Round 20
// 54.672 us; speedup vs baseline: 1.4286x; 1.1247x over previous
//
#include <hip/hip_runtime.h>
#include <hip/hip_bf16.h>

typedef __attribute__((ext_vector_type(8))) short short8;
typedef __attribute__((ext_vector_type(4))) float f32x4;
typedef __attribute__((ext_vector_type(16))) float f32x16;
typedef __attribute__((ext_vector_type(2))) int int2v;

#define N_TOK 8192
#define D_HALF 64
#define D_FULL 128
#define QB 128                     // q rows per block (4 sub-tiles of 32)
#define KQ 2048                    // keys per block (k-split 4)
#define CHUNK 128                  // keys staged per chunk (32KB K + 32KB V)
#define NCH (KQ / CHUNK)           // 16
#define OSTR 132
#define RSC 1.2011224087864498f    // sqrt(log2(e)): scores arrive in log2 domain
#define MFIX 94.0f                 // fixed softmax max: > 64*log2(e)=92.33 bound

// pack two f32 into one bf16x2 word (lo=a, hi=b) -- single v_cvt_pk_bf16_f32
static __device__ __forceinline__ unsigned cvtpk(float a, float b)
{
    unsigned r;
    asm("v_cvt_pk_bf16_f32 %0, %1, %2" : "=v"(r) : "v"(a), "v"(b));
    return r;
}

// raw native exp2 (scores are <= -1.7 here; <= -126 flushes to 0, fine)
static __device__ __forceinline__ float exp2raw(float x)
{
    float r;
    asm("v_exp_f32 %0, %1" : "=v"(r) : "v"(x));
    return r;
}

// Fused precompute, vectorized 16B stores (R19, verified).
__global__ __launch_bounds__(256) void precompute_kernel(
    const float* __restrict__ mag, const float* __restrict__ phase,
    __hip_bfloat16* __restrict__ Kf, __hip_bfloat16* __restrict__ Vf)
{
    const int bid = blockIdx.x;
    const int tid = threadIdx.x;

    if (bid < 256) {
        // ---- K-pack ----
        int g  = bid * 256 + tid;        // 65536 threads
        int n  = g >> 3;
        int db = g & 7;
        const f32x4* mp = reinterpret_cast<const f32x4*>(mag + (size_t)n * 64 + db * 8);
        const f32x4* pp = reinterpret_cast<const f32x4*>(phase + (size_t)n * 64 + db * 8);
        f32x4 m0 = mp[0], m1 = mp[1];
        f32x4 p0 = pp[0], p1 = pp[1];
        float kc[8], ks_[8];
        #pragma unroll
        for (int j = 0; j < 4; ++j) {
            float s, c;
            sincosf(p0[j], &s, &c);
            kc[j]  = m0[j] * c * RSC;
            ks_[j] = m0[j] * s * RSC;
        }
        #pragma unroll
        for (int j = 0; j < 4; ++j) {
            float s, c;
            sincosf(p1[j], &s, &c);
            kc[4 + j]  = m1[j] * c * RSC;
            ks_[4 + j] = m1[j] * s * RSC;
        }
        union { unsigned w[4]; short8 v; } vc, vs;
        #pragma unroll
        for (int j = 0; j < 4; ++j) {
            vc.w[j] = cvtpk(kc[2 * j], kc[2 * j + 1]);
            vs.w[j] = cvtpk(ks_[2 * j], ks_[2 * j + 1]);
        }
        short8* K8 = reinterpret_cast<short8*>(Kf);
        int offc = ((n >> 5) * 16 + db) * 32 + (n & 31);       // short8 units
        int offs = ((n >> 5) * 16 + 8 + db) * 32 + (n & 31);
        K8[offc] = vc.v;
        K8[offs] = vs.v;
    } else {
        // ---- V-pack (LDS transpose; no trig) ----
        __shared__ float T[32][65];
        int vb   = bid - 256;            // 0..511
        int tile = vb >> 1;              // 0..255 (32-row tiles)
        int h    = vb & 1;               // 0 = mag, 1 = phase
        const float* src = h ? phase : mag;
        {
            int r = tid >> 3, cp = (tid & 7) * 8;
            const f32x4* sp = reinterpret_cast<const f32x4*>(src + ((size_t)tile * 32 + r) * 64 + cp);
            f32x4 a = sp[0], b = sp[1];
            #pragma unroll
            for (int j = 0; j < 4; ++j) { T[r][cp + j] = a[j]; T[r][cp + 4 + j] = b[j]; }
        }
        __syncthreads();

        int dv = tid & 63;
        int nb = tid >> 6;
        int n0 = tile * 32 + nb * 8;
        int dv_eff = dv + 64 * h;
        union { unsigned w[4]; short8 v; } pk;
        #pragma unroll
        for (int j = 0; j < 4; ++j)
            pk.w[j] = cvtpk(T[nb * 8 + 2 * j][dv], T[nb * 8 + 2 * j + 1][dv]);
        short8* V8 = reinterpret_cast<short8*>(Vf);
        int off8 = ((n0 >> 4) * 4 + (dv_eff >> 5)) * 64 + ((n0 >> 3) & 1) * 32 + (dv_eff & 31);
        V8[off8] = pk.v;
    }
}

// R14/R18 structure + ROUND-20 changes:
//  (1) QK accumulator split st_a/st_b: halves the 8-deep dependent MFMA
//      chain (MfmaUtil 2000cy/chunk vs 512cy issue-min = latency exposure).
//  (2) raw v_exp_f32 for the softmax exps.
// Fixed-max softmax, counted-vmcnt double-buffer DMA, bf16 partials.
__global__ __launch_bounds__(512, 2) void attn_kernel(
    const short8* __restrict__ Kf8, const short8* __restrict__ Vf8,
    __hip_bfloat16* __restrict__ Opart, float* __restrict__ Sp)
{
    __shared__ __align__(16) char smem[132096];  // 2 x (K 32KB | V 32KB) + merge sums

    const int tid  = threadIdx.x;
    const int wid  = tid >> 6;     // 0..7
    const int lane = tid & 63;
    const int li   = lane & 31;
    const int hi   = lane >> 5;
    const int qh   = wid >> 1;     // q sub-tile 0..3
    const int kp   = wid & 1;      // key panel group

    const int bid  = blockIdx.x;
    const int qt   = bid >> 2;     // 0..63
    const int kq   = bid & 3;      // key quarter
    const int rot  = bid & (NCH - 1);

    float (*O_lds)[32][OSTR] = (float (*)[32][OSTR])smem;   // merge reuse
    float* s_base = (float*)(smem + 67584);                 // [4][32]
    auto sslot = [&](int slot) -> float* { return s_base + slot * 32; };

    auto stageKV = [&](int ck, char* lbase) {
        const char* gk = (const char*)(Kf8 + (size_t)ck * 2048);
        const char* gv = (const char*)(Vf8 + (size_t)ck * 2048);
        #pragma unroll
        for (int j = 0; j < 4; ++j)
            __builtin_amdgcn_global_load_lds(
                (const __attribute__((address_space(1))) void*)(gk + j * 8192 + tid * 16),
                (__attribute__((address_space(3))) void*)(lbase + j * 8192 + tid * 16),
                16, 0, 0);
        #pragma unroll
        for (int j = 0; j < 4; ++j)
            __builtin_amdgcn_global_load_lds(
                (const __attribute__((address_space(1))) void*)(gv + j * 8192 + tid * 16),
                (__attribute__((address_space(3))) void*)(lbase + 32768 + j * 8192 + tid * 16),
                16, 0, 0);
    };
    auto ck_of = [&](int t) { return kq * NCH + ((t + rot) & (NCH - 1)); };

    // Q fragments FIRST (oldest in vmcnt queue, so counted waits stay exact)
    short8 bq[8];
    {
        const short8* qp = Kf8 + (size_t)(qt * 4 + qh) * 512;
        #pragma unroll
        for (int ks = 0; ks < 8; ++ks)
            bq[ks] = qp[(ks * 2 + hi) * 32 + li];
    }

    f32x16 acc[4];
    #pragma unroll
    for (int d = 0; d < 4; ++d) acc[d] = (f32x16)(0.0f);
    float srow = 0.0f;

    stageKV(ck_of(0), smem);
    stageKV(ck_of(1), smem + 65536);
    asm volatile("s_waitcnt vmcnt(8)");     // bq + S(0) retired; S(1) flying
    __builtin_amdgcn_s_barrier();

    for (int t = 0; t < NCH; ++t) {
        char* base = smem + (t & 1) * 65536;
        const short8* ldsK = (const short8*)base;
        const short8* ldsV = (const short8*)(base + 32768);

        #pragma unroll
        for (int pp = 0; pp < 2; ++pp) {
            const int panel = kp + 2 * pp;

            // ---- S^T = K.Q: TWO independent 4-deep chains (latency fix) ----
            f32x16 sa = (f32x16)(-MFIX);   // C-init folds the softmax subtract
            f32x16 sb = (f32x16)(0.0f);
            __builtin_amdgcn_s_setprio(1);
            #pragma unroll
            for (int ks = 0; ks < 4; ++ks) {
                short8 kfa = ldsK[panel * 512 + (ks * 2 + hi) * 32 + li];
                short8 kfb = ldsK[panel * 512 + ((ks + 4) * 2 + hi) * 32 + li];
                sa = __builtin_amdgcn_mfma_f32_32x32x16_bf16(kfa, bq[ks], sa, 0, 0, 0);
                sb = __builtin_amdgcn_mfma_f32_32x32x16_bf16(kfb, bq[ks + 4], sb, 0, 0, 0);
            }
            __builtin_amdgcn_s_setprio(0);
            f32x16 st;
            #pragma unroll
            for (int r = 0; r < 16; ++r) st[r] = sa[r] + sb[r];

            // ---- P = exp2(st) (native v_exp_f32); row-sum only ----
            #pragma unroll
            for (int r = 0; r < 16; ++r) st[r] = exp2raw(st[r]);
            float sm[8];
            #pragma unroll
            for (int r = 0; r < 8; ++r) sm[r] = st[r] + st[r + 8];
            float ss = ((sm[0] + sm[1]) + (sm[2] + sm[3]))
                     + ((sm[4] + sm[5]) + (sm[6] + sm[7]));
            srow += ss + __shfl_xor(ss, 32);

            // ---- PV: pack P (cvt_pk) -> permlane repack -> 8 MFMA ----
            #pragma unroll
            for (int c = 0; c < 2; ++c) {
                const int b = 8 * c;
                unsigned a0 = cvtpk(st[b + 0], st[b + 1]);
                unsigned a1 = cvtpk(st[b + 2], st[b + 3]);
                unsigned b0 = cvtpk(st[b + 4], st[b + 5]);
                unsigned b1 = cvtpk(st[b + 6], st[b + 7]);
                int2v r0 = __builtin_amdgcn_permlane32_swap((int)a0, (int)b0, false, false);
                int2v r1 = __builtin_amdgcn_permlane32_swap((int)a1, (int)b1, false, false);
                union { int w[4]; short8 v; } u;
                u.w[0] = r0[0]; u.w[1] = r1[0]; u.w[2] = r0[1]; u.w[3] = r1[1];

                const short8* vp = ldsV + (panel * 2 + c) * 256 + hi * 32 + li;
                __builtin_amdgcn_s_setprio(1);
                #pragma unroll
                for (int d = 0; d < 4; ++d) {
                    short8 vf = vp[d * 64];
                    acc[d] = __builtin_amdgcn_mfma_f32_32x32x16_bf16(vf, u.v, acc[d], 0, 0, 0);
                }
                __builtin_amdgcn_s_setprio(0);
            }
        }

        __builtin_amdgcn_s_barrier();            // all waves done reading buf
        if (t + 2 < NCH) {
            stageKV(ck_of(t + 2), base);         // refill this buffer
            asm volatile("s_waitcnt vmcnt(8)");  // S(t+1) landed, S(t+2) flying
        } else {
            asm volatile("s_waitcnt vmcnt(0)");  // epilogue drain
        }
        __builtin_amdgcn_s_barrier();            // next buffer ready for all
    }

    // ---- in-block merge over kp (pure sums; fixed max everywhere) ----
    auto store_partial = [&](int slot) {
        #pragma unroll
        for (int d = 0; d < 4; ++d)
            #pragma unroll
            for (int rr = 0; rr < 4; ++rr) {
                f32x4 v;
                #pragma unroll
                for (int j = 0; j < 4; ++j) v[j] = acc[d][4 * rr + j];
                *reinterpret_cast<f32x4*>(&O_lds[slot][li][d * 32 + 8 * rr + 4 * hi]) = v;
            }
        if (hi == 0) sslot(slot)[li] = srow;
    };
    auto merge_partial = [&](int slot) {
        srow += sslot(slot)[li];
        #pragma unroll
        for (int d = 0; d < 4; ++d)
            #pragma unroll
            for (int rr = 0; rr < 4; ++rr) {
                f32x4 v = *reinterpret_cast<const f32x4*>(&O_lds[slot][li][d * 32 + 8 * rr + 4 * hi]);
                #pragma unroll
                for (int j = 0; j < 4; ++j)
                    acc[d][4 * rr + j] += v[j];
            }
    };

    __syncthreads();                         // staging dead; reuse as merge space
    if (kp == 1) store_partial(qh);
    __syncthreads();
    if (kp == 0) merge_partial(qh);
    __syncthreads();
    if (kp == 0) store_partial(qh);
    __syncthreads();

    // ---- write UNNORMALIZED per-block partial as bf16 ----
    #pragma unroll
    for (int u0 = 0; u0 < 4; ++u0) {
        int u  = tid + u0 * 512;           // 0..2047
        int q  = u >> 4;                   // 0..127
        int dg = (u & 15) * 8;             // 0..120
        int grp = q >> 5, qq = q & 31;
        f32x4 o0 = *reinterpret_cast<const f32x4*>(&O_lds[grp][qq][dg]);
        f32x4 o1 = *reinterpret_cast<const f32x4*>(&O_lds[grp][qq][dg + 4]);
        union { unsigned w[4]; short8 v; } pk;
        pk.w[0] = cvtpk(o0[0], o0[1]);
        pk.w[1] = cvtpk(o0[2], o0[3]);
        pk.w[2] = cvtpk(o1[0], o1[1]);
        pk.w[3] = cvtpk(o1[2], o1[3]);
        size_t pidx = (size_t)bid * QB + q;
        *reinterpret_cast<short8*>(&Opart[pidx * D_FULL + dg]) = pk.v;
        if (dg == 0) Sp[pidx] = sslot(grp)[qq];   // merged sum from LDS (f32)
    }
}

// combine the four k-quarter bf16 partials per q-row (pure sums), normalize
__global__ __launch_bounds__(256) void merge4_kernel(
    const __hip_bfloat16* __restrict__ Opart, const float* __restrict__ Sp,
    float* __restrict__ out)
{
    int i   = blockIdx.x * 256 + threadIdx.x;   // 131072 total, 8 floats each
    int row = i >> 4;                           // 0..8191
    int dg  = (i & 15) * 8;                     // 0..120
    int qt  = row >> 7, qq = row & 127;
    float S = 0.0f;
    f32x4 o0 = (f32x4)(0.0f), o1 = (f32x4)(0.0f);
    #pragma unroll
    for (int k = 0; k < 4; ++k) {
        size_t pidx = (size_t)(qt * 4 + k) * QB + qq;
        S += Sp[pidx];
        short8 v = *reinterpret_cast<const short8*>(&Opart[pidx * D_FULL + dg]);
        #pragma unroll
        for (int j = 0; j < 8; ++j) {
            unsigned short us = (unsigned short)v[j];
            unsigned wu = ((unsigned)us) << 16;
            float f = *reinterpret_cast<float*>(&wu);
            if (j < 4) o0[j] += f; else o1[j - 4] += f;
        }
    }
    float inv = 1.0f / S;
    #pragma unroll
    for (int j = 0; j < 4; ++j) { o0[j] *= inv; o1[j] *= inv; }
    float* dst = (dg < D_HALF)
        ? out + (size_t)row * D_HALF + dg
        : out + (size_t)N_TOK * D_HALF + (size_t)row * D_HALF + (dg - D_HALF);
    *reinterpret_cast<f32x4*>(dst)     = o0;
    *reinterpret_cast<f32x4*>(dst + 4) = o1;
}

extern "C" void kernel_launch(void* const* d_in, const int* in_sizes, int n_in,
                              void* d_out, int out_size, void* d_ws, size_t ws_size,
                              hipStream_t stream)
{
    const float* mag   = (const float*)d_in[0];
    const float* phase = (const float*)d_in[1];
    float* out = (float*)d_out;

    char* ws = (char*)d_ws;
    __hip_bfloat16* Kf = (__hip_bfloat16*)ws;                    // 2 MB
    __hip_bfloat16* Vf = Kf + (size_t)N_TOK * D_FULL;            // 2 MB
    __hip_bfloat16* Opart = (__hip_bfloat16*)(ws + 4u * 1024 * 1024);  // 8 MB
    float* Sp = (float*)(ws + 13u * 1024 * 1024);                // 128 KB

    precompute_kernel<<<768, 256, 0, stream>>>(mag, phase, Kf, Vf);
    attn_kernel<<<256, 512, 0, stream>>>((const short8*)Kf, (const short8*)Vf, Opart, Sp);
    merge4_kernel<<<512, 256, 0, stream>>>(Opart, Sp, out);
}